// Round 6
// baseline (3372.308 us; speedup 1.0000x reference)
//
#include <hip/hip_runtime.h>
#include <hip/hip_bf16.h>

#define DMODEL 1024
#define NH     16
#define BB     4
#define TT     2048
#define BT     (BB * TT)   // 8192

typedef __bf16 bf16_t;
typedef __attribute__((ext_vector_type(8))) __bf16 bf16x8;
typedef __attribute__((ext_vector_type(2))) __bf16 bf16x2;
typedef __attribute__((ext_vector_type(4))) float f32x4;

// chunked-scan geometry
#define LDF    68
#define FB     4352
#define LDH    36
#define HB     2304

#define C_B0   0
#define C_B1   FB
#define C_B2   (2*FB)
#define C_B3   (3*FB)
#define C_B4   (4*FB)
#define C_B5   (5*FB)
#define C_HV   (4*FB)
#define C_HC   (4*FB + HB)
#define C_HG   (4*FB + 2*HB)
#define C_HK   (4*FB + 3*HB)
#define C_B6   (4*FB + 4*HB)
#define C_B7   (C_B6 + FB)
#define C_POOL (C_B7 + FB)

// direct global->LDS, 16B per lane (linear dest = wave base + lane*16)
#define GLOAD16(g, l) __builtin_amdgcn_global_load_lds( \
    (const __attribute__((address_space(1))) void*)(g), \
    (__attribute__((address_space(3))) void*)(l), 16, 0, 0)

// ===========================================================================
// x fp32 -> bf16 (8192*1024 elems, grid 4096 x 256, 8 elems/thread)
// ===========================================================================
__global__ __launch_bounds__(256) void xcvt_kernel(
    const float* __restrict__ x, bf16_t* __restrict__ xb)
{
    const size_t i = ((size_t)blockIdx.x * 256 + threadIdx.x) * 8;
    float4 a = *(const float4*)&x[i];
    float4 b = *(const float4*)&x[i + 4];
    bf16x8 h;
    h[0]=(bf16_t)a.x; h[1]=(bf16_t)a.y; h[2]=(bf16_t)a.z; h[3]=(bf16_t)a.w;
    h[4]=(bf16_t)b.x; h[5]=(bf16_t)b.y; h[6]=(bf16_t)b.z; h[7]=(bf16_t)b.w;
    *(bf16x8*)&xb[i] = h;
}

// ===========================================================================
// Weight prep: W[k][n] fp32 -> Wt[n][k] bf16
// ===========================================================================
__global__ __launch_bounds__(256) void wprep_kernel(
    const float* __restrict__ w0, const float* __restrict__ w1,
    const float* __restrict__ w2, const float* __restrict__ w3,
    const float* __restrict__ w4, const float* __restrict__ w5,
    bf16_t* __restrict__ d0, bf16_t* __restrict__ d1,
    bf16_t* __restrict__ d2, bf16_t* __restrict__ d3,
    bf16_t* __restrict__ d4, bf16_t* __restrict__ d5)
{
    __shared__ float tile[64][65];
    const float* src; bf16_t* dst;
    switch (blockIdx.z) {
        case 0: src = w0; dst = d0; break;
        case 1: src = w1; dst = d1; break;
        case 2: src = w2; dst = d2; break;
        case 3: src = w3; dst = d3; break;
        case 4: src = w4; dst = d4; break;
        default: src = w5; dst = d5; break;
    }
    const int k0 = blockIdx.x * 64, n0 = blockIdx.y * 64;
    const int tid = threadIdx.x;
    const int r = tid >> 2, c = (tid & 3) * 16;
#pragma unroll
    for (int q = 0; q < 4; ++q)
        *(float4*)&tile[r][c + q * 4] =
            *(const float4*)&src[(size_t)(k0 + r) * 1024 + n0 + c + q * 4];
    __syncthreads();
    const int rn = tid >> 2, ck = (tid & 3) * 16;
    bf16x8 h0, h1;
#pragma unroll
    for (int j = 0; j < 8; ++j) h0[j] = (bf16_t)tile[ck + j][rn];
#pragma unroll
    for (int j = 0; j < 8; ++j) h1[j] = (bf16_t)tile[ck + 8 + j][rn];
    *(bf16x8*)&dst[(size_t)(n0 + rn) * 1024 + k0 + ck]     = h0;
    *(bf16x8*)&dst[(size_t)(n0 + rn) * 1024 + k0 + ck + 8] = h1;
}

// ===========================================================================
// bf16 NT MFMA GEMM v2: out = A(8192x1024 bf16) * Bt(1024x1024 bf16, n-major)^T
// 128x128 tile, BK=32, double-buffered LDS via global_load_lds (T3 2-phase),
// XOR-swizzled layout: quad ^= (row>>1)&3 (pre-swizzled source + swizzled read).
// mode 0: proj layout; mode 1: proj + sigmoid(x+bias); mode 2: row-major fp32.
// ===========================================================================
__global__ __launch_bounds__(256) void gemm_bf16_kernel(
    const bf16_t* __restrict__ A, const bf16_t* __restrict__ Bt,
    const float* __restrict__ bias, float* __restrict__ out, int mode)
{
    __shared__ __align__(16) bf16_t Asm[2][4096];   // [buf][128 rows * 32 k]
    __shared__ __align__(16) bf16_t Bsm[2][4096];

    const int tid  = threadIdx.x;
    const int lane = tid & 63, wave = tid >> 6;
    const int wr = (wave >> 1) * 64, wc = (wave & 1) * 64;
    const int l15 = lane & 15, l16 = lane >> 4;
    const int m0 = blockIdx.x * 128, n0 = blockIdx.y * 128;

    // staging: thread tid covers LDS bytes tid*16 (row sr, stored quad qs);
    // source quad pre-swizzled so read side can use the same XOR.
    const int sr = tid >> 2;
    const int qg = (tid & 3) ^ ((sr >> 1) & 3);
    const bf16_t* Ab = A  + (size_t)(m0 + sr) * 1024 + qg * 8;
    const bf16_t* Bb = Bt + (size_t)(n0 + sr) * 1024 + qg * 8;
    const size_t rstep = (size_t)64 * 1024;

    f32x4 acc[4][4];
#pragma unroll
    for (int i = 0; i < 4; ++i)
#pragma unroll
        for (int j = 0; j < 4; ++j) acc[i][j] = (f32x4){0.f, 0.f, 0.f, 0.f};

    // fragment offsets (bf16 units), swizzled read side
    int offA[4], offB[4];
#pragma unroll
    for (int m = 0; m < 4; ++m) {
        const int R = wr + m * 16 + l15;
        offA[m] = R * 32 + ((l16 ^ ((R >> 1) & 3)) * 8);
    }
#pragma unroll
    for (int n = 0; n < 4; ++n) {
        const int R = wc + n * 16 + l15;
        offB[n] = R * 32 + ((l16 ^ ((R >> 1) & 3)) * 8);
    }

    // prologue: stage k=0 into buf 0
    GLOAD16(Ab,         &Asm[0][tid * 8]);
    GLOAD16(Ab + rstep, &Asm[0][2048 + tid * 8]);
    GLOAD16(Bb,         &Bsm[0][tid * 8]);
    GLOAD16(Bb + rstep, &Bsm[0][2048 + tid * 8]);
    __syncthreads();

    int cur = 0;
    for (int t = 0; t < 32; ++t) {
        if (t + 1 < 32) {   // issue next-tile staging before compute
            const int k1 = (t + 1) * 32;
            GLOAD16(Ab + k1,         &Asm[cur ^ 1][tid * 8]);
            GLOAD16(Ab + rstep + k1, &Asm[cur ^ 1][2048 + tid * 8]);
            GLOAD16(Bb + k1,         &Bsm[cur ^ 1][tid * 8]);
            GLOAD16(Bb + rstep + k1, &Bsm[cur ^ 1][2048 + tid * 8]);
        }
        bf16x8 af[4], bfr[4];
#pragma unroll
        for (int m = 0; m < 4; ++m) af[m] = *(const bf16x8*)&Asm[cur][offA[m]];
#pragma unroll
        for (int n = 0; n < 4; ++n) bfr[n] = *(const bf16x8*)&Bsm[cur][offB[n]];
#pragma unroll
        for (int m = 0; m < 4; ++m)
#pragma unroll
            for (int n = 0; n < 4; ++n)
                acc[m][n] = __builtin_amdgcn_mfma_f32_16x16x32_bf16(
                    af[m], bfr[n], acc[m][n], 0, 0, 0);
        __syncthreads();   // drains vmcnt+lgkm: next buf ready, cur buf reusable
        cur ^= 1;
    }

    // epilogue: C/D layout col = lane&15, row = (lane>>4)*4 + reg  [m89, r5-verified]
#pragma unroll
    for (int n = 0; n < 4; ++n) {
        const int col = n0 + wc + n * 16 + l15;
        const int h = col >> 6, d = col & 63;
        const float bb = (mode == 1) ? bias[col] : 0.f;
#pragma unroll
        for (int m = 0; m < 4; ++m) {
#pragma unroll
            for (int r = 0; r < 4; ++r) {
                const int row = m0 + wr + m * 16 + l16 * 4 + r;
                float v = acc[m][n][r];
                if (mode == 2) {
                    out[(size_t)row * 1024 + col] = v;
                } else {
                    if (mode == 1) v = 1.f / (1.f + expf(-(v + bb)));
                    const int b_ = row >> 11, t_ = row & 2047;
                    out[((size_t)((b_ * NH + h) * TT + t_) << 6) + d] = v;
                }
            }
        }
    }
}

// ===========================================================================
// fp32 tiled GEMM (fallback path only)
// ===========================================================================
__global__ __launch_bounds__(256) void gemm_kernel(
    const float* __restrict__ A,
    const float* __restrict__ Bw,
    const float* __restrict__ bias,
    float* __restrict__ out,
    int mode)
{
    __shared__ __align__(16) float As[16][132];
    __shared__ __align__(16) float Bs[16][132];

    const int tid = threadIdx.x;
    const int tm = tid >> 4;
    const int tn = tid & 15;
    const int m0 = blockIdx.x * 128;
    const int n0 = blockIdx.y * 128;

    float acc[8][8];
#pragma unroll
    for (int i = 0; i < 8; ++i)
#pragma unroll
        for (int j = 0; j < 8; ++j) acc[i][j] = 0.f;

    const int arow = tid >> 2;
    const int akq  = (tid & 3) * 4;
    const int brow = tid >> 5;
    const int bnq  = (tid & 31) * 4;

    for (int k0 = 0; k0 < 1024; k0 += 16) {
#pragma unroll
        for (int it = 0; it < 2; ++it) {
            const int mr = it * 64 + arow;
            const float4 va = *(const float4*)(A + (size_t)(m0 + mr) * 1024 + k0 + akq);
            As[akq + 0][mr] = va.x;
            As[akq + 1][mr] = va.y;
            As[akq + 2][mr] = va.z;
            As[akq + 3][mr] = va.w;
        }
#pragma unroll
        for (int it = 0; it < 2; ++it) {
            const int kr = it * 8 + brow;
            const float4 vb = *(const float4*)(Bw + (size_t)(k0 + kr) * 1024 + n0 + bnq);
            *(float4*)&Bs[kr][bnq] = vb;
        }
        __syncthreads();
#pragma unroll
        for (int k = 0; k < 16; ++k) {
            float a[8], b[8];
            *(float4*)&a[0] = *(const float4*)&As[k][tm * 8];
            *(float4*)&a[4] = *(const float4*)&As[k][tm * 8 + 4];
            *(float4*)&b[0] = *(const float4*)&Bs[k][tn * 8];
            *(float4*)&b[4] = *(const float4*)&Bs[k][tn * 8 + 4];
#pragma unroll
            for (int i = 0; i < 8; ++i)
#pragma unroll
                for (int j = 0; j < 8; ++j)
                    acc[i][j] = fmaf(a[i], b[j], acc[i][j]);
        }
        __syncthreads();
    }

    if (mode == 2) {
#pragma unroll
        for (int i = 0; i < 8; ++i) {
            const int m = m0 + tm * 8 + i;
            float* dst = out + (size_t)m * 1024 + n0 + tn * 8;
            *(float4*)dst       = make_float4(acc[i][0], acc[i][1], acc[i][2], acc[i][3]);
            *((float4*)dst + 1) = make_float4(acc[i][4], acc[i][5], acc[i][6], acc[i][7]);
        }
    } else {
        const int nn = n0 + tn * 8;
        const int h = nn >> 6;
        const int d = nn & 63;
        float bb[8];
        if (mode == 1) {
#pragma unroll
            for (int j = 0; j < 8; ++j) bb[j] = bias[nn + j];
        }
#pragma unroll
        for (int i = 0; i < 8; ++i) {
            const int m  = m0 + tm * 8 + i;
            const int b_ = m >> 11;
            const int t_ = m & 2047;
            float v[8];
#pragma unroll
            for (int j = 0; j < 8; ++j) {
                float x = acc[i][j];
                if (mode == 1) x = 1.f / (1.f + expf(-(x + bb[j])));
                v[j] = x;
            }
            float* dst = out + ((size_t)((b_ * NH + h) * TT + t_) << 6) + d;
            *(float4*)dst       = make_float4(v[0], v[1], v[2], v[3]);
            *((float4*)dst + 1) = make_float4(v[4], v[5], v[6], v[7]);
        }
    }
}

// ===========================================================================
// chunked-path helpers
// ===========================================================================
__device__ inline float4 f4mul(float4 a, float4 b) {
    return make_float4(a.x*b.x, a.y*b.y, a.z*b.z, a.w*b.w);
}
__device__ inline float4 f4div(float4 a, float4 b) {
    return make_float4(a.x/b.x, a.y/b.y, a.z/b.z, a.w/b.w);
}

__device__ inline void stage64(float* sm, int off, const float* __restrict__ g, int tid)
{
    const int row = tid >> 2, c0 = (tid & 3) * 16;
#pragma unroll
    for (int q = 0; q < 4; ++q) {
        float4 v = *(const float4*)&g[(size_t)row * 64 + c0 + q * 4];
        *(float4*)&sm[off + row * LDF + c0 + q * 4] = v;
    }
}

__device__ inline void stage32(float* sm, int off, const float* __restrict__ g, int vh, int tid)
{
    const int row = tid >> 2, c0 = (tid & 3) * 8;
#pragma unroll
    for (int q = 0; q < 2; ++q) {
        float4 v = *(const float4*)&g[(size_t)row * 64 + vh * 32 + c0 + q * 4];
        *(float4*)&sm[off + row * LDH + c0 + q * 4] = v;
    }
}

template<bool SWA>
__device__ inline void mmTN_g(const float* sm, int offA, int offB,
                              float* __restrict__ gout, int tid)
{
    const int tm = tid >> 4, tn = tid & 15;
    float acc[4][4] = {};
    for (int k0 = 0; k0 < 64; k0 += 4) {
        float4 a[4], b[4];
#pragma unroll
        for (int q = 0; q < 4; ++q) {
            const int row = k0 + q;
            const int ca = SWA ? (tm ^ ((row >> 2) & 7)) : tm;
            a[q] = *(const float4*)&sm[offA + row * LDF + ca * 4];
            b[q] = *(const float4*)&sm[offB + row * LDF + tn * 4];
        }
#pragma unroll
        for (int q = 0; q < 4; ++q) {
            const float* ap = (const float*)&a[q];
            const float* bp = (const float*)&b[q];
#pragma unroll
            for (int i = 0; i < 4; ++i)
#pragma unroll
                for (int j = 0; j < 4; ++j)
                    acc[i][j] = fmaf(ap[i], bp[j], acc[i][j]);
        }
    }
#pragma unroll
    for (int i = 0; i < 4; ++i)
        *(float4*)&gout[(size_t)(tm*4 + i) * 64 + tn * 4] =
            make_float4(acc[i][0], acc[i][1], acc[i][2], acc[i][3]);
}

__device__ inline void mmNT_lds(float* sm, int offA, int offB, int offC,
                                int mask, int tid)
{
    const int tm = tid >> 4, tn = tid & 15;
    float acc[4][4] = {};
    for (int k0 = 0; k0 < 64; k0 += 4) {
        float4 a[4], b[4];
#pragma unroll
        for (int i = 0; i < 4; ++i)
            a[i] = *(const float4*)&sm[offA + (tm*4 + i) * LDF + k0];
        const int cc = ((k0 >> 2) ^ (tn & 7)) * 4;
#pragma unroll
        for (int j = 0; j < 4; ++j)
            b[j] = *(const float4*)&sm[offB + (tn*4 + j) * LDF + cc];
#pragma unroll
        for (int i = 0; i < 4; ++i) {
            const float* ap = (const float*)&a[i];
#pragma unroll
            for (int j = 0; j < 4; ++j) {
                const float* bp = (const float*)&b[j];
                acc[i][j] = fmaf(ap[0], bp[0], acc[i][j]);
                acc[i][j] = fmaf(ap[1], bp[1], acc[i][j]);
                acc[i][j] = fmaf(ap[2], bp[2], acc[i][j]);
                acc[i][j] = fmaf(ap[3], bp[3], acc[i][j]);
            }
        }
    }
#pragma unroll
    for (int i = 0; i < 4; ++i) {
        const int m = tm*4 + i;
#pragma unroll
        for (int j = 0; j < 4; ++j) {
            const int n = tn*4 + j;
            float v = acc[i][j];
            if (mask == 1 && n > m)  v = 0.f;
            if (mask == 2 && n >= m) v = 0.f;
            sm[offC + m * LDF + n] = v;
        }
    }
}

template<bool SWB, bool NEG>
__device__ inline void mmNN_acc(const float* sm, int offA, int offB,
                                float (&acc)[4][4], int tid)
{
    const int tm = tid >> 4, tn = tid & 15;
    for (int k0 = 0; k0 < 64; k0 += 4) {
        float4 a[4], b[4];
#pragma unroll
        for (int i = 0; i < 4; ++i)
            a[i] = *(const float4*)&sm[offA + (tm*4 + i) * LDF + k0];
        const int ctn = SWB ? ((tn ^ ((k0 >> 2) & 7)) * 4) : (tn * 4);
#pragma unroll
        for (int q = 0; q < 4; ++q)
            b[q] = *(const float4*)&sm[offB + (k0 + q) * LDF + ctn];
#pragma unroll
        for (int i = 0; i < 4; ++i) {
            const float* ap = (const float*)&a[i];
#pragma unroll
            for (int q = 0; q < 4; ++q) {
                const float av = NEG ? -ap[q] : ap[q];
                const float* bp = (const float*)&b[q];
#pragma unroll
                for (int j = 0; j < 4; ++j)
                    acc[i][j] = fmaf(av, bp[j], acc[i][j]);
            }
        }
    }
}

__device__ inline void mmNN_lds(float* sm, int offA, int offB, int offC, int tid)
{
    float acc[4][4] = {};
    mmNN_acc<false, false>(sm, offA, offB, acc, tid);
    const int tm = tid >> 4, tn = tid & 15;
#pragma unroll
    for (int i = 0; i < 4; ++i)
        *(float4*)&sm[offC + (tm*4 + i) * LDF + tn * 4] =
            make_float4(acc[i][0], acc[i][1], acc[i][2], acc[i][3]);
}

template<bool NEG>
__device__ inline void mmNN32_acc(const float* sm, int offA, int offB,
                                  float (&acc)[4][2], int tid)
{
    const int tm = tid >> 4, tn = tid & 15;
    for (int k0 = 0; k0 < 64; k0 += 4) {
        float4 a[4];
        float2 b[4];
#pragma unroll
        for (int i = 0; i < 4; ++i)
            a[i] = *(const float4*)&sm[offA + (tm*4 + i) * LDF + k0];
#pragma unroll
        for (int q = 0; q < 4; ++q)
            b[q] = *(const float2*)&sm[offB + (k0 + q) * LDH + tn * 2];
#pragma unroll
        for (int i = 0; i < 4; ++i) {
            const float* ap = (const float*)&a[i];
#pragma unroll
            for (int q = 0; q < 4; ++q) {
                const float av = NEG ? -ap[q] : ap[q];
                acc[i][0] = fmaf(av, b[q].x, acc[i][0]);
                acc[i][1] = fmaf(av, b[q].y, acc[i][1]);
            }
        }
    }
}

// ===========================================================================
// Kernel A: per-(chain,chunk) summaries
// ===========================================================================
__global__ __launch_bounds__(256) void chunk_sum_kernel(
    const float* __restrict__ Qp, const float* __restrict__ Kp,
    const float* __restrict__ Vp, const float* __restrict__ AKp,
    const float* __restrict__ ACp,
    float* __restrict__ ASg, float* __restrict__ ACg,
    float* __restrict__ Mg,  float* __restrict__ AGvg,
    float* __restrict__ DKg, float* __restrict__ DCg,
    int chainBase)
{
    __shared__ float sm[6 * FB];
    const int bid = blockIdx.x, tid = threadIdx.x;
    const int ch = chainBase + (bid >> 5), ck = bid & 31;
    const size_t ib = ((size_t)ch * TT + ck * 64) * 64;

    stage64(sm, 0,      Qp  + ib, tid);
    stage64(sm, FB,     Kp  + ib, tid);
    stage64(sm, 2*FB,   AKp + ib, tid);
    stage64(sm, 3*FB,   ACp + ib, tid);
    stage64(sm, 4*FB,   Vp  + ib, tid);
    __syncthreads();

    if (tid < 128) {
        const int i = tid & 63;
        const int off = (tid < 64) ? 2*FB : 3*FB;
        float p = 1.f;
        for (int t = 0; t < 64; ++t) {
            p *= sm[off + t * LDF + i];
            sm[off + t * LDF + i] = p;
        }
        if (tid < 64) DKg[(size_t)bid * 64 + i] = p;
        else          DCg[(size_t)bid * 64 + i] = p;
    }
    __syncthreads();

    {
        const int row = tid >> 2, cb = (tid & 3) * 16;
        const int sx = (row >> 2) & 7;
#pragma unroll
        for (int w = 0; w < 4; ++w) {
            const int c = cb + w * 4;
            float4 q  = *(const float4*)&sm[0    + row * LDF + c];
            float4 k  = *(const float4*)&sm[FB   + row * LDF + c];
            float4 pk = *(const float4*)&sm[2*FB + row * LDF + c];
            float4 pc = *(const float4*)&sm[3*FB + row * LDF + c];
            *(float4*)&sm[0  + row * LDF + c] = f4mul(k, pc);
            *(float4*)&sm[FB + row * LDF + c] = f4div(k, pk);
            const int csw = (((c >> 2) ^ sx) << 2);
            *(float4*)&sm[5*FB + row * LDF + csw] = f4div(q, pc);
        }
    }
    __syncthreads();

    mmTN_g<false>(sm, FB,   FB,   ASg  + (size_t)bid * 4096, tid);
    mmTN_g<true >(sm, 5*FB, 4*FB, ACg  + (size_t)bid * 4096, tid);
    mmTN_g<false>(sm, FB,   0,    Mg   + (size_t)bid * 4096, tid);
    mmNT_lds(sm, 0, 5*FB, 2*FB, 2, tid);
    __syncthreads();
    mmNN_lds(sm, 2*FB, 4*FB, 3*FB, tid);
    __syncthreads();
    mmTN_g<false>(sm, FB, 3*FB, AGvg + (size_t)bid * 4096, tid);
}

// ===========================================================================
// Kernel B: sequential chunk-state composition, dist-1 software prefetch
// ===========================================================================
__global__ __launch_bounds__(256) void state_scan_kernel(
    float* __restrict__ ASg, float* __restrict__ ACg,
    const float* __restrict__ Mg,  float* __restrict__ AGvg,
    const float* __restrict__ DKg, const float* __restrict__ DCg)
{
    __shared__ float sm[6 * FB];   // 0:S FB:C 2FB:G 3FB:M(buf0) 4FB:MC 5FB:M(buf1)
    __shared__ float dkv[2][64], dcv[2][64];
    const int lch = blockIdx.x, tid = threadIdx.x;

    for (int e = tid; e < 3 * FB; e += 256) sm[e] = 0.f;

    const int row = tid >> 2, c0 = (tid & 3) * 16;

    // prefetch chunk 0
    float4 r_as[4], r_ac[4], r_ag[4];
    {
        const size_t sb = (size_t)(lch * 32) * 4096;
#pragma unroll
        for (int q = 0; q < 4; ++q) {
            const size_t e = sb + row * 64 + c0 + q * 4;
            r_as[q] = *(const float4*)&ASg[e];
            r_ac[q] = *(const float4*)&ACg[e];
            r_ag[q] = *(const float4*)&AGvg[e];
        }
        stage64(sm, 3 * FB, Mg + sb, tid);
        if (tid < 64)       dkv[0][tid]      = DKg[sb / 64 + tid];
        else if (tid < 128) dcv[0][tid - 64] = DCg[sb / 64 + tid - 64];
    }
    __syncthreads();

    for (int ck = 0; ck < 32; ++ck) {
        const int cb = ck & 1;
        const size_t sb = (size_t)(lch * 32 + ck) * 4096;

        // 1. write BEFORE-chunk states into the aliased summary slots
#pragma unroll
        for (int q = 0; q < 4; ++q) {
            const int c = c0 + q * 4;
            const size_t e = sb + row * 64 + c;
            *(float4*)&ASg[e]  = *(const float4*)&sm[0    + row * LDF + c];
            *(float4*)&ACg[e]  = *(const float4*)&sm[FB   + row * LDF + c];
            *(float4*)&AGvg[e] = *(const float4*)&sm[2*FB + row * LDF + c];
        }

        // 2. prefetch chunk ck+1 (regs + other M buffer + gate vecs)
        float4 n_as[4], n_ac[4], n_ag[4];
        if (ck + 1 < 32) {
            const size_t nb = sb + 4096;
#pragma unroll
            for (int q = 0; q < 4; ++q) {
                const size_t e = nb + row * 64 + c0 + q * 4;
                n_as[q] = *(const float4*)&ASg[e];
                n_ac[q] = *(const float4*)&ACg[e];
                n_ag[q] = *(const float4*)&AGvg[e];
            }
            stage64(sm, (cb ? 3 : 5) * FB, Mg + nb, tid);
            if (tid < 64)       dkv[cb ^ 1][tid]      = DKg[nb / 64 + tid];
            else if (tid < 128) dcv[cb ^ 1][tid - 64] = DCg[nb / 64 + tid - 64];
        }

        // 3. MC = M * C (current M buffer)
        mmNN_lds(sm, (cb ? 5 : 3) * FB, FB, 4 * FB, tid);
        __syncthreads();   // drains vmcnt: prefetch regs valid after this

        // 4. update states in LDS
        const float dki = dkv[cb][row], dci = dcv[cb][row];
#pragma unroll
        for (int w = 0; w < 4; ++w) {
            const int c = c0 + w * 4;
            float4 dkj = *(const float4*)&dkv[cb][c];
            float4 s   = *(float4*)&sm[0 + row * LDF + c];
            s.x = dki * dkj.x * (s.x + r_as[w].x);
            s.y = dki * dkj.y * (s.y + r_as[w].y);
            s.z = dki * dkj.z * (s.z + r_as[w].z);
            s.w = dki * dkj.w * (s.w + r_as[w].w);
            *(float4*)&sm[0 + row * LDF + c] = s;

            float4 cc = *(float4*)&sm[FB + row * LDF + c];
            cc.x = dci * (cc.x + r_ac[w].x);
            cc.y = dci * (cc.y + r_ac[w].y);
            cc.z = dci * (cc.z + r_ac[w].z);
            cc.w = dci * (cc.w + r_ac[w].w);
            *(float4*)&sm[FB + row * LDF + c] = cc;

            float4 g  = *(float4*)&sm[2*FB + row * LDF + c];
            float4 mc = *(const float4*)&sm[4*FB + row * LDF + c];
            g.x = dki * (g.x + mc.x + r_ag[w].x);
            g.y = dki * (g.y + mc.y + r_ag[w].y);
            g.z = dki * (g.z + mc.z + r_ag[w].z);
            g.w = dki * (g.w + mc.w + r_ag[w].w);
            *(float4*)&sm[2*FB + row * LDF + c] = g;
        }
        __syncthreads();

        if (ck + 1 < 32) {
#pragma unroll
            for (int q = 0; q < 4; ++q) {
                r_as[q] = n_as[q]; r_ac[q] = n_ac[q]; r_ag[q] = n_ag[q];
            }
        }
    }
}

// ===========================================================================
// Kernel C: per-(chain,chunk) outputs (of_bf16: write Of as bf16)
// ===========================================================================
__global__ __launch_bounds__(256) void chunk_out_kernel(
    const float* __restrict__ Qp, const float* __restrict__ Kp,
    const float* __restrict__ Vp, const float* __restrict__ AKp,
    const float* __restrict__ ACp,
    const float* __restrict__ S0g, const float* __restrict__ C0g,
    const float* __restrict__ G0g, float* __restrict__ Of,
    int chainBase, int of_bf16)
{
    __shared__ float sm[C_POOL];
    const int bid = blockIdx.x, tid = threadIdx.x;
    const int ch = chainBase + (bid >> 5), ck = bid & 31;
    const size_t ib = ((size_t)ch * TT + ck * 64) * 64;

    stage64(sm, C_B0, Qp  + ib, tid);
    stage64(sm, C_B1, Kp  + ib, tid);
    stage64(sm, C_B2, AKp + ib, tid);
    stage64(sm, C_B3, ACp + ib, tid);
    __syncthreads();

    if (tid < 128) {
        const int i = tid & 63;
        const int off = (tid < 64) ? C_B2 : C_B3;
        float p = 1.f;
        for (int t = 0; t < 64; ++t) {
            p *= sm[off + t * LDF + i];
            sm[off + t * LDF + i] = p;
        }
    }
    __syncthreads();

    {
        const int row = tid >> 2, cb = (tid & 3) * 16;
        const int sx = (row >> 2) & 7;
#pragma unroll
        for (int w = 0; w < 4; ++w) {
            const int c = cb + w * 4;
            float4 q  = *(const float4*)&sm[C_B0 + row * LDF + c];
            float4 k  = *(const float4*)&sm[C_B1 + row * LDF + c];
            float4 pk = *(const float4*)&sm[C_B2 + row * LDF + c];
            float4 pc = *(const float4*)&sm[C_B3 + row * LDF + c];
            *(float4*)&sm[C_B0 + row * LDF + c] = f4mul(q, pk);
            *(float4*)&sm[C_B1 + row * LDF + c] = f4mul(k, pc);
            *(float4*)&sm[C_B2 + row * LDF + c] = f4mul(pk, pc);
            const int csw = (((c >> 2) ^ sx) << 2);
            *(float4*)&sm[C_B4 + row * LDF + csw] = f4div(q, pc);
            *(float4*)&sm[C_B5 + row * LDF + csw] = f4div(k, pk);
        }
    }
    __syncthreads();

    stage64(sm, C_B6, S0g + (size_t)bid * 4096, tid);
    mmNT_lds(sm, C_B0, C_B5, C_B3, 1, tid);
    __syncthreads();

    {
        float acc[4][4] = {};
        mmNN_acc<false, false>(sm, C_B0, C_B6, acc, tid);
        mmNN_acc<true,  false>(sm, C_B3, C_B5, acc, tid);
        const int tm = tid >> 4, tn = tid & 15;
#pragma unroll
        for (int i = 0; i < 4; ++i) {
            const int m = tm * 4 + i;
            const float4 pp = *(const float4*)&sm[C_B2 + m * LDF + tn * 4];
            *(float4*)&sm[C_B7 + m * LDF + tn * 4] =
                make_float4(acc[i][0] * pp.x, acc[i][1] * pp.y,
                            acc[i][2] * pp.z, acc[i][3] * pp.w);
        }
    }
    __syncthreads();

    mmNT_lds(sm, C_B1, C_B4, C_B2, 2, tid);
    mmNT_lds(sm, C_B7, C_B4, C_B6, 1, tid);
    __syncthreads();

    const int b_ = ch >> 4, h_ = ch & 15;
    const int tm = tid >> 4, tn = tid & 15;

    for (int vh = 0; vh < 2; ++vh) {
        stage32(sm, C_HV, Vp + ib,                  vh, tid);
        stage32(sm, C_HC, C0g + (size_t)bid * 4096, vh, tid);
        stage32(sm, C_HG, G0g + (size_t)bid * 4096, vh, tid);
        __syncthreads();
        {
            float acc[4][2] = {};
            mmNN32_acc<false>(sm, C_B1, C_HC, acc, tid);
            mmNN32_acc<false>(sm, C_B2, C_HV, acc, tid);
#pragma unroll
            for (int i = 0; i < 4; ++i) {
                sm[C_HK + (tm*4 + i) * LDH + tn*2 + 0] = acc[i][0];
                sm[C_HK + (tm*4 + i) * LDH + tn*2 + 1] = acc[i][1];
            }
        }
        __syncthreads();
        {
            float acc[4][2] = {};
            mmNN32_acc<false>(sm, C_B7, C_HC, acc, tid);
            mmNN32_acc<false>(sm, C_B6, C_HV, acc, tid);
            mmNN32_acc<true >(sm, C_B0, C_HG, acc, tid);
            mmNN32_acc<true >(sm, C_B3, C_HK, acc, tid);
#pragma unroll
            for (int i = 0; i < 4; ++i) {
                const int t = ck * 64 + tm * 4 + i;
                const size_t o = ((size_t)b_ * TT + t) * 1024 + h_ * 64 + vh * 32 + tn * 2;
                if (of_bf16) {
                    bf16x2 v;
                    v[0] = (bf16_t)acc[i][0];
                    v[1] = (bf16_t)acc[i][1];
                    *(bf16x2*)&((bf16_t*)Of)[o] = v;
                } else {
                    *(float2*)&Of[o] = make_float2(acc[i][0], acc[i][1]);
                }
            }
        }
        __syncthreads();
    }
}

// ===========================================================================
// Fallback: round-1 sequential scan
// ===========================================================================
__global__ __launch_bounds__(256) void scan_kernel(
    const float* __restrict__ Q,  const float* __restrict__ Kv,
    const float* __restrict__ V,  const float* __restrict__ AK,
    const float* __restrict__ AC, float* __restrict__ Oflat)
{
    const int bh  = blockIdx.x;
    const int b_  = bh >> 4;
    const int h_  = bh & 15;
    const int tid = threadIdx.x;
    const int c   = tid >> 2;
    const int r4  = tid & 3;
    const int i0  = r4 * 16;

    __shared__ __align__(16) float vals[2][5][64];
    __shared__ __align__(16) float u_lds[64];

    const size_t base = (size_t)bh * TT * 64;
    const float* arrs[5] = {Q + base, Kv + base, V + base, AK + base, AC + base};

    float sk[16], cv[16], g[16];
#pragma unroll
    for (int r = 0; r < 16; ++r) { sk[r] = 0.f; cv[r] = 0.f; g[r] = 0.f; }

    const bool loader = (tid < 80);
    const int  larr = tid >> 4;
    const int  loff = (tid & 15) * 4;
    float4 pf[2];

    if (loader) {
        pf[0] = *(const float4*)(arrs[larr] + 0 * 64 + loff);
        pf[1] = *(const float4*)(arrs[larr] + 1 * 64 + loff);
        *(float4*)&vals[0][larr][loff] = pf[0];
    }
    __syncthreads();

    for (int t = 0; t < TT; ++t) {
        const int cur = t & 1;
        if (loader && (t + 2) < TT)
            pf[cur] = *(const float4*)(arrs[larr] + (size_t)(t + 2) * 64 + loff);

        float qv[16], kv[16], ak[16], ac[16];
#pragma unroll
        for (int r = 0; r < 16; r += 4) {
            *(float4*)&qv[r] = *(const float4*)&vals[cur][0][i0 + r];
            *(float4*)&kv[r] = *(const float4*)&vals[cur][1][i0 + r];
            *(float4*)&ak[r] = *(const float4*)&vals[cur][3][i0 + r];
            *(float4*)&ac[r] = *(const float4*)&vals[cur][4][i0 + r];
        }
        const float vc  = vals[cur][2][c];
        const float kc  = vals[cur][1][c];
        const float akc = vals[cur][3][c];

        float pk[4] = {0.f, 0.f, 0.f, 0.f};
#pragma unroll
        for (int r = 0; r < 16; ++r) {
            const float s = ac[r] * cv[r];
            pk[r & 3] = fmaf(kv[r], s, pk[r & 3]);
            cv[r] = fmaf(qv[r], vc, s);
        }
        float ktc = (pk[0] + pk[1]) + (pk[2] + pk[3]);
        ktc += __shfl_xor(ktc, 1);
        ktc += __shfl_xor(ktc, 2);

        float pu[4] = {0.f, 0.f, 0.f, 0.f};
        float pw[4] = {0.f, 0.f, 0.f, 0.f};
#pragma unroll
        for (int r = 0; r < 16; ++r) {
            g[r]  = fmaf(ak[r], g[r], kv[r] * ktc);
            sk[r] = fmaf(ak[r] * akc, sk[r], kv[r] * kc);
            pu[r & 3] = fmaf(qv[r], sk[r], pu[r & 3]);
            pw[r & 3] = fmaf(qv[r], g[r],  pw[r & 3]);
        }
        float u = (pu[0] + pu[1]) + (pu[2] + pu[3]);
        u += __shfl_xor(u, 1);
        u += __shfl_xor(u, 2);
        float w = (pw[0] + pw[1]) + (pw[2] + pw[3]);
        w += __shfl_xor(w, 1);
        w += __shfl_xor(w, 2);

        if (r4 == 0) u_lds[c] = u;
        __syncthreads();

        float po[4] = {0.f, 0.f, 0.f, 0.f};
#pragma unroll
        for (int r = 0; r < 16; r += 4) {
            const float4 uu = *(const float4*)&u_lds[i0 + r];
            po[0] = fmaf(uu.x, cv[r + 0], po[0]);
            po[1] = fmaf(uu.y, cv[r + 1], po[1]);
            po[2] = fmaf(uu.z, cv[r + 2], po[2]);
            po[3] = fmaf(uu.w, cv[r + 3], po[3]);
        }
        float o = (po[0] + po[1]) + (po[2] + po[3]);
        o += __shfl_xor(o, 1);
        o += __shfl_xor(o, 2);

        if (r4 == 0)
            Oflat[((size_t)b_ * TT + t) * 1024 + h_ * 64 + c] = o - w;

        if (loader && (t + 1) < TT)
            *(float4*)&vals[cur ^ 1][larr][loff] = pf[cur ^ 1];
        __syncthreads();
    }
}

// ===========================================================================
extern "C" void kernel_launch(void* const* d_in, const int* in_sizes, int n_in,
                              void* d_out, int out_size, void* d_ws, size_t ws_size,
                              hipStream_t stream)
{
    const float* x    = (const float*)d_in[0];
    const float* W_q  = (const float*)d_in[1];
    const float* W_k  = (const float*)d_in[2];
    const float* W_v  = (const float*)d_in[3];
    const float* Wg_K = (const float*)d_in[4];
    const float* bg_K = (const float*)d_in[5];
    const float* Wg_C = (const float*)d_in[6];
    const float* bg_C = (const float*)d_in[7];
    const float* W_o  = (const float*)d_in[8];

    float* ws = (float*)d_ws;
    const size_t S1  = (size_t)BB * NH * TT * 64;  // 8,388,608 floats
    const size_t S1h = S1 / 2;                     // bf16 array (S1 elems) in floats
    const size_t WT1 = (size_t)1024 * 1024 / 2;    // one bf16 weight in floats
    float* Qp = ws + 0 * S1;
    float* Kp = ws + 1 * S1;
    float* Vp = ws + 2 * S1;
    float* AK = ws + 3 * S1;
    float* AC = ws + 4 * S1;

    dim3 blk(256);
    const size_t wsF = ws_size / 4;

    // layout (mfma path): [5 proj fp32][Ofb bf16][WtO][ xb | WtP  <- aliased by chunk bufs ]
    const size_t offOfb   = 5 * S1;
    const size_t offWtO   = 5 * S1 + S1h;
    const size_t chunkBase = offWtO + WT1;
    const bool mfma_ok = wsF >= chunkBase + S1h + 5 * WT1;

    if (mfma_ok) {
        bf16_t* Ofb = (bf16_t*)(ws + offOfb);
        bf16_t* WtO = (bf16_t*)(ws + offWtO);
        bf16_t* xb  = (bf16_t*)(ws + chunkBase);
        bf16_t* WtP = (bf16_t*)(ws + chunkBase + S1h);

        xcvt_kernel<<<dim3(4096), blk, 0, stream>>>(x, xb);
        wprep_kernel<<<dim3(16, 16, 6), blk, 0, stream>>>(
            W_q, W_k, W_v, Wg_K, Wg_C, W_o,
            WtP + 0 * 1048576, WtP + 1 * 1048576, WtP + 2 * 1048576,
            WtP + 3 * 1048576, WtP + 4 * 1048576, WtO);

        dim3 grid(BT / 128, 1024 / 128);
        gemm_bf16_kernel<<<grid, blk, 0, stream>>>(xb, WtP + 0 * 1048576, nullptr, Qp, 0);
        gemm_bf16_kernel<<<grid, blk, 0, stream>>>(xb, WtP + 1 * 1048576, nullptr, Kp, 0);
        gemm_bf16_kernel<<<grid, blk, 0, stream>>>(xb, WtP + 2 * 1048576, nullptr, Vp, 0);
        gemm_bf16_kernel<<<grid, blk, 0, stream>>>(xb, WtP + 3 * 1048576, bg_K,    AK, 1);
        gemm_bf16_kernel<<<grid, blk, 0, stream>>>(xb, WtP + 4 * 1048576, bg_C,    AC, 1);

        // chunked scan; buffers alias xb+WtP (dead after projections)
        const size_t avail = wsF - chunkBase;
        int P = 0;
        for (int cand = 64; cand >= 4; cand >>= 1) {
            const size_t ex = (size_t)cand * 32 * 4096 * 4 + (size_t)cand * 32 * 64 * 2;
            if (avail >= ex) { P = cand; break; }
        }
        if (P > 0) {
            const size_t CS = (size_t)P * 32 * 4096;
            float* ASg  = ws + chunkBase;
            float* ACg  = ASg + CS;
            float* Mg   = ACg + CS;
            float* AGvg = Mg  + CS;
            float* DKg  = AGvg + CS;
            float* DCg  = DKg + (size_t)P * 32 * 64;
            for (int p0 = 0; p0 < 64; p0 += P) {
                chunk_sum_kernel<<<dim3(P * 32), blk, 0, stream>>>(
                    Qp, Kp, Vp, AK, AC, ASg, ACg, Mg, AGvg, DKg, DCg, p0);
                state_scan_kernel<<<dim3(P), blk, 0, stream>>>(
                    ASg, ACg, Mg, AGvg, DKg, DCg);
                chunk_out_kernel<<<dim3(P * 32), blk, 0, stream>>>(
                    Qp, Kp, Vp, AK, AC, ASg, ACg, AGvg, (float*)Ofb, p0, 1);
            }
        } else {
            // no chunk space (can't happen given mfma_ok margin, but keep safe):
            scan_kernel<<<dim3(64), blk, 0, stream>>>(Qp, Kp, Vp, AK, AC, (float*)Ofb);
        }

        gemm_bf16_kernel<<<grid, blk, 0, stream>>>(Ofb, WtO, nullptr, (float*)d_out, 2);
    } else {
        // fp32 fallback (round-4 path)
        float* Of = ws + 5 * S1;
        dim3 grid(BT / 128, 1024 / 128);
        gemm_kernel<<<grid, blk, 0, stream>>>(x, W_q,  nullptr, Qp, 0);
        gemm_kernel<<<grid, blk, 0, stream>>>(x, W_k,  nullptr, Kp, 0);
        gemm_kernel<<<grid, blk, 0, stream>>>(x, W_v,  nullptr, Vp, 0);
        gemm_kernel<<<grid, blk, 0, stream>>>(x, Wg_K, bg_K,    AK, 1);
        gemm_kernel<<<grid, blk, 0, stream>>>(x, Wg_C, bg_C,    AC, 1);

        const size_t availF = (wsF > 6 * S1) ? (wsF - 6 * S1) : 0;
        int P = 0;
        for (int cand = 64; cand >= 4; cand >>= 1) {
            const size_t ex = (size_t)cand * 32 * 4096 * 4 + (size_t)cand * 32 * 64 * 2;
            if (availF >= ex) { P = cand; break; }
        }
        if (P > 0) {
            const size_t CS = (size_t)P * 32 * 4096;
            float* ASg  = ws + 6 * S1;
            float* ACg  = ASg + CS;
            float* Mg   = ACg + CS;
            float* AGvg = Mg  + CS;
            float* DKg  = AGvg + CS;
            float* DCg  = DKg + (size_t)P * 32 * 64;
            for (int p0 = 0; p0 < 64; p0 += P) {
                chunk_sum_kernel<<<dim3(P * 32), blk, 0, stream>>>(
                    Qp, Kp, Vp, AK, AC, ASg, ACg, Mg, AGvg, DKg, DCg, p0);
                state_scan_kernel<<<dim3(P), blk, 0, stream>>>(
                    ASg, ACg, Mg, AGvg, DKg, DCg);
                chunk_out_kernel<<<dim3(P * 32), blk, 0, stream>>>(
                    Qp, Kp, Vp, AK, AC, ASg, ACg, AGvg, Of, p0, 0);
            }
        } else {
            scan_kernel<<<dim3(64), blk, 0, stream>>>(Qp, Kp, Vp, AK, AC, Of);
        }
        gemm_kernel<<<grid, blk, 0, stream>>>(Of, W_o, nullptr, (float*)d_out, 2);
    }
}